// Round 10
// baseline (414.750 us; speedup 1.0000x reference)
//
#include <hip/hip_runtime.h>

#define NB 16
#define CDIM 512
#define NHEAD 8
#define DHEAD 64
#define NSEQ 4096
#define O3 1536

typedef __attribute__((ext_vector_type(8))) short short8;
typedef __attribute__((ext_vector_type(4))) float f32x4;
typedef __attribute__((ext_vector_type(4))) unsigned u32x4;
typedef __attribute__((ext_vector_type(2))) unsigned u32x2;
typedef __attribute__((ext_vector_type(4))) float fvec4;

__device__ __forceinline__ float bf2f(unsigned short u){
  union { unsigned u; float f; } v; v.u = ((unsigned)u) << 16; return v.f;
}
__device__ __forceinline__ unsigned short f2bf(float f){
  union { float f; unsigned u; } v; v.f = f;
  unsigned r = v.u + 0x7fffu + ((v.u >> 16) & 1u);
  return (unsigned short)(r >> 16);
}
__device__ __forceinline__ unsigned pack2(float a, float b){
  return (unsigned)f2bf(a) | ((unsigned)f2bf(b) << 16);
}
__device__ __forceinline__ void gld_lds16(const void* g, void* l){
  __builtin_amdgcn_global_load_lds(
      (const __attribute__((address_space(1))) unsigned*)g,
      (__attribute__((address_space(3))) unsigned*)l, 16, 0, 0);
}

// ---- w_qkv f32 -> bf16 ----
__global__ __launch_bounds__(256) void k_conv_w(const float* __restrict__ w,
                                                unsigned short* __restrict__ o){
  int i = (blockIdx.x*256 + threadIdx.x)*4;
  fvec4 v = *(const fvec4*)(w + i);
  u32x2 p; p[0] = pack2(v[0], v[1]); p[1] = pack2(v[2], v[3]);
  *(u32x2*)(o + i) = p;
}

// ---- x [b][c][n] f32 -> xT [b][n][c] bf16; 16B reads, 16B writes ----
__global__ __launch_bounds__(256) void k_transpose_x(const float* __restrict__ x,
                                                     unsigned short* __restrict__ xT){
  __shared__ unsigned short tile[64][65];
  int b = blockIdx.z, c0 = blockIdx.y*64, n0 = blockIdx.x*64;
  int t = threadIdx.x;
  const float* xb = x + ((size_t)b*CDIM + c0)*NSEQ + n0;
  #pragma unroll
  for (int i=0;i<4;i++){
    int idx = t + i*256;
    int r = idx>>4, c4 = (idx&15)*4;
    fvec4 v = *(const fvec4*)(xb + (size_t)r*NSEQ + c4);
    tile[r][c4]   = f2bf(v[0]);
    tile[r][c4+1] = f2bf(v[1]);
    tile[r][c4+2] = f2bf(v[2]);
    tile[r][c4+3] = f2bf(v[3]);
  }
  __syncthreads();
  unsigned short* ob = xT + ((size_t)b*NSEQ + n0)*CDIM + c0;
  #pragma unroll
  for (int i=0;i<2;i++){
    int chunk = t + i*256;
    int r = chunk>>3, c8 = (chunk&7)*8;
    u32x4 p;
    #pragma unroll
    for (int k=0;k<4;k++)
      p[k] = (unsigned)tile[c8+2*k][r] | ((unsigned)tile[c8+2*k+1][r] << 16);
    *(u32x4*)(ob + (size_t)r*CDIM + c8) = p;
  }
}

// ---- k/v GEMM: r6 BK=64 split-half body + hoisted staging pointers.
//      k-tiles (o0<512) write bf16(exp(k)); v-tiles write raw bf16. ----
__global__ __launch_bounds__(256) void k_gemm_kv(const unsigned short* __restrict__ A,
                                                 const unsigned short* __restrict__ Bt,
                                                 unsigned short* __restrict__ KV){
  __shared__ unsigned short As[2][128*32];   // 16 KB
  __shared__ unsigned short Bs[2][128*32];   // 16 KB
  int b = blockIdx.z;
  int n0 = blockIdx.x*128, o0 = blockIdx.y*128;
  const unsigned short* Bb = Bt + (size_t)b*NSEQ*CDIM;
  unsigned short* Cb = KV + (size_t)b*1024*NSEQ;
  int t = threadIdx.x, w = t>>6, l = t&63;
  int lr = l&15, kq = (l>>4)*8;
  int wr = (w>>1)*64, wc = (w&1)*64;
  int srow = t>>2, skc = (t&3)*8;
  // carried staging pointers (advance +64 elems/K-step); +32 variants fold to imm
  const unsigned short* pa0 = A  + (size_t)(o0+srow)*CDIM + skc;
  const unsigned short* pa1 = A  + (size_t)(o0+64+srow)*CDIM + skc;
  const unsigned short* pb0 = Bb + (size_t)(n0+srow)*CDIM + skc;
  const unsigned short* pb1 = Bb + (size_t)(n0+64+srow)*CDIM + skc;
  char* dA = (char*)As[0] + t*16;   // As[1] = +8192B; it1 = +4096B
  char* dB = (char*)Bs[0] + t*16;
  f32x4 acc[4][4];
  #pragma unroll
  for (int mi=0;mi<4;mi++)
    #pragma unroll
    for (int ni=0;ni<4;ni++) acc[mi][ni] = (f32x4){0.f,0.f,0.f,0.f};
  for (int k0=0;k0<CDIM;k0+=64){
    gld_lds16(pa0,    dA);
    gld_lds16(pa0+32, dA+8192);
    gld_lds16(pa1,    dA+4096);
    gld_lds16(pa1+32, dA+12288);
    gld_lds16(pb0,    dB);
    gld_lds16(pb0+32, dB+8192);
    gld_lds16(pb1,    dB+4096);
    gld_lds16(pb1+32, dB+12288);
    __syncthreads();
    #pragma unroll
    for (int h=0;h<2;++h){
      short8 af[4], bfv[4];
      #pragma unroll
      for (int mi=0;mi<4;mi++) af[mi]  = *(const short8*)&As[h][(wr + mi*16 + lr)*32 + kq];
      #pragma unroll
      for (int ni=0;ni<4;ni++) bfv[ni] = *(const short8*)&Bs[h][(wc + ni*16 + lr)*32 + kq];
      #pragma unroll
      for (int mi=0;mi<4;mi++)
        #pragma unroll
        for (int ni=0;ni<4;ni++)
          acc[mi][ni] = __builtin_amdgcn_mfma_f32_16x16x32_bf16(af[mi], bfv[ni], acc[mi][ni], 0, 0, 0);
    }
    __syncthreads();
    pa0 += 64; pa1 += 64; pb0 += 64; pb1 += 64;
  }
  if (o0 < 512){   // k channels: fuse exp
    #pragma unroll
    for (int mi=0;mi<4;mi++)
      #pragma unroll
      for (int ni=0;ni<4;ni++)
        #pragma unroll
        for (int r=0;r<4;r++){
          int row = o0 + wr + mi*16 + (l>>4)*4 + r;
          int col = n0 + wc + ni*16 + lr;
          Cb[(size_t)row*NSEQ + col] = f2bf(__expf(acc[mi][ni][r]));
        }
  } else {
    #pragma unroll
    for (int mi=0;mi<4;mi++)
      #pragma unroll
      for (int ni=0;ni<4;ni++)
        #pragma unroll
        for (int r=0;r<4;r++){
          int row = o0 + wr + mi*16 + (l>>4)*4 + r;
          int col = n0 + wc + ni*16 + lr;
          Cb[(size_t)row*NSEQ + col] = f2bf(acc[mi][ni][r]);
        }
  }
}

// ---- q GEMM (r6 BK=64 split halves + hoisted pointers) + in-reg softmax ----
#define TS 136
__global__ __launch_bounds__(256) void k_gemm_q(const unsigned short* __restrict__ A,
                                                const unsigned short* __restrict__ Bt,
                                                unsigned short* __restrict__ qsmT){
  __shared__ unsigned short smem[128*128];   // 32 KB: A halves @0/8192B, B halves @16384/24576B
  int b = blockIdx.z;
  int n0 = blockIdx.x*128, o0 = blockIdx.y*128;
  const unsigned short* Bb = Bt + (size_t)b*NSEQ*CDIM;
  int t = threadIdx.x, w = t>>6, l = t&63;
  int lr = l&15, kq = (l>>4)*8;
  int wr = (w>>1)*64, wc = (w&1)*64;
  int srow = t>>2, skc = (t&3)*8;
  const unsigned short* pa0 = A  + (size_t)(o0+srow)*CDIM + skc;
  const unsigned short* pa1 = A  + (size_t)(o0+64+srow)*CDIM + skc;
  const unsigned short* pb0 = Bb + (size_t)(n0+srow)*CDIM + skc;
  const unsigned short* pb1 = Bb + (size_t)(n0+64+srow)*CDIM + skc;
  char* dA = (char*)smem + t*16;
  char* dB = (char*)smem + 16384 + t*16;
  f32x4 acc[4][4];
  #pragma unroll
  for (int mi=0;mi<4;mi++)
    #pragma unroll
    for (int ni=0;ni<4;ni++) acc[mi][ni] = (f32x4){0.f,0.f,0.f,0.f};
  for (int k0=0;k0<CDIM;k0+=64){
    gld_lds16(pa0,    dA);
    gld_lds16(pa0+32, dA+8192);
    gld_lds16(pa1,    dA+4096);
    gld_lds16(pa1+32, dA+12288);
    gld_lds16(pb0,    dB);
    gld_lds16(pb0+32, dB+8192);
    gld_lds16(pb1,    dB+4096);
    gld_lds16(pb1+32, dB+12288);
    __syncthreads();
    #pragma unroll
    for (int h=0;h<2;++h){
      const unsigned short* Ash = smem + h*4096;
      const unsigned short* Bsh = smem + 8192 + h*4096;
      short8 af[4], bfv[4];
      #pragma unroll
      for (int mi=0;mi<4;mi++) af[mi]  = *(const short8*)&Ash[(wr + mi*16 + lr)*32 + kq];
      #pragma unroll
      for (int ni=0;ni<4;ni++) bfv[ni] = *(const short8*)&Bsh[(wc + ni*16 + lr)*32 + kq];
      #pragma unroll
      for (int mi=0;mi<4;mi++)
        #pragma unroll
        for (int ni=0;ni<4;ni++)
          acc[mi][ni] = __builtin_amdgcn_mfma_f32_16x16x32_bf16(af[mi], bfv[ni], acc[mi][ni], 0, 0, 0);
    }
    __syncthreads();
    pa0 += 64; pa1 += 64; pb0 += 64; pb1 += 64;
  }
  // in-register softmax over d (wave's 64 rows = one head) per column
  unsigned pk[4][4][2];
  #pragma unroll
  for (int ni=0;ni<4;ni++){
    float mx = -1e30f;
    #pragma unroll
    for (int mi=0;mi<4;mi++)
      #pragma unroll
      for (int r=0;r<4;r++) mx = fmaxf(mx, acc[mi][ni][r]);
    mx = fmaxf(mx, __shfl_xor(mx, 16, 64));
    mx = fmaxf(mx, __shfl_xor(mx, 32, 64));
    float s = 0.f;
    #pragma unroll
    for (int mi=0;mi<4;mi++)
      #pragma unroll
      for (int r=0;r<4;r++){
        float p = __expf(acc[mi][ni][r] - mx);
        acc[mi][ni][r] = p; s += p;
      }
    s += __shfl_xor(s, 16, 64);
    s += __shfl_xor(s, 32, 64);
    float inv = 0.125f / s;
    #pragma unroll
    for (int mi=0;mi<4;mi++){
      pk[mi][ni][0] = pack2(acc[mi][ni][0]*inv, acc[mi][ni][1]*inv);
      pk[mi][ni][1] = pack2(acc[mi][ni][2]*inv, acc[mi][ni][3]*inv);
    }
  }
  #pragma unroll
  for (int ck=0;ck<2;++ck){
    if ((w&1) == ck){
      #pragma unroll
      for (int mi=0;mi<4;mi++)
        #pragma unroll
        for (int ni=0;ni<4;ni++){
          int idx = (ni*16 + lr)*TS + wr + mi*16 + (l>>4)*4;
          u32x2 p; p[0] = pk[mi][ni][0]; p[1] = pk[mi][ni][1];
          *(u32x2*)&smem[idx] = p;
        }
    }
    __syncthreads();
    int col = t>>2, rs = (t&3)*32;
    unsigned short* dst = qsmT + ((size_t)b*NSEQ + n0 + ck*64 + col)*CDIM + o0 + rs;
    #pragma unroll
    for (int j=0;j<4;++j)
      *(u32x4*)(dst + j*8) = *(const u32x4*)&smem[col*TS + rs + j*8];
    __syncthreads();
  }
}

// ---- partial context over n-chunk; k already holds bf16(exp(k)) ----
__global__ __launch_bounds__(256) void k_context(const unsigned short* __restrict__ KV,
                                                 float* __restrict__ ctx4,
                                                 float* __restrict__ sump){
  __shared__ unsigned short Vs[64*64];
  int m = blockIdx.x, b = blockIdx.y, ch = blockIdx.z;
  int t = threadIdx.x, w = t>>6, l = t&63;
  int lr = l&15, kq = (l>>4)*8;
  const unsigned short* kbase = KV + ((size_t)b*1024 + m*64)*NSEQ;
  const unsigned short* vbase = KV + ((size_t)b*1024 + 512 + m*64)*NSEQ;
  int irow = w*16 + lr;
  int sub = l>>4;
  int nbeg = ch*1024;
  float rsum = 0.f;
  f32x4 acc[4];
  #pragma unroll
  for (int jf=0;jf<4;++jf) acc[jf] = (f32x4){0.f,0.f,0.f,0.f};
  for (int n0=nbeg;n0<nbeg+1024;n0+=64){
    #pragma unroll
    for (int it=0;it<2;++it){
      int chunk = it*256 + t;
      int row = chunk>>3, kc = (chunk&7)*8;
      gld_lds16(vbase + (size_t)row*NSEQ + n0 + kc, (char*)Vs + (size_t)chunk*16);
    }
    __syncthreads();
    #pragma unroll
    for (int kk=0;kk<2;++kk){
      u32x4 kraw = *(const u32x4*)(kbase + (size_t)irow*NSEQ + n0 + kk*32 + kq);
      short8 af = *(const short8*)&kraw;        // bit-identical: values are exp(k) bf16
      #pragma unroll
      for (int c=0;c<4;++c){
        unsigned u = kraw[c];
        rsum += bf2f((unsigned short)u) + bf2f((unsigned short)(u>>16));
      }
      #pragma unroll
      for (int jf=0;jf<4;++jf){
        short8 bv = *(const short8*)&Vs[(jf*16+lr)*64 + kk*32 + kq];
        acc[jf] = __builtin_amdgcn_mfma_f32_16x16x32_bf16(af, bv, acc[jf], 0, 0, 0);
      }
    }
    __syncthreads();
  }
  rsum += __shfl_xor(rsum, 16, 64);
  rsum += __shfl_xor(rsum, 32, 64);
  size_t sbase = (((size_t)ch*NB + b)*NHEAD + m)*64;
  if (sub == 0) sump[sbase + irow] = rsum;
  float* cb = ctx4 + (((size_t)ch*NB + b)*NHEAD + m)*4096;
  #pragma unroll
  for (int jf=0;jf<4;++jf)
    #pragma unroll
    for (int r=0;r<4;++r){
      int i = w*16 + (l>>4)*4 + r;
      int j = jf*16 + lr;
      cb[i*64 + j] = acc[jf][r];
    }
}

// ---- W_eff: plain-sum merge of 4 chunk-partials, then fold w_out ----
__global__ __launch_bounds__(256) void k_weff(const float* __restrict__ ctx4,
                                              const float* __restrict__ sump,
                                              const float* __restrict__ wout,
                                              unsigned short* __restrict__ weff){
  __shared__ float cs[64][65];
  __shared__ float invZ[64];
  int m = blockIdx.x, b = blockIdx.y, z = blockIdx.z;
  int t = threadIdx.x, w = t>>6, l = t&63;
  const size_t chs = (size_t)NB*NHEAD*4096;
  const size_t sts = (size_t)NB*NHEAD*64;
  size_t sb = ((size_t)b*NHEAD + m)*64;
  if (t < 64){
    float Z = sump[sb + t] + sump[sb + sts + t]
            + sump[sb + 2*sts + t] + sump[sb + 3*sts + t];
    invZ[t] = 1.f/Z;
  }
  __syncthreads();
  const float* cb = ctx4 + ((size_t)b*NHEAD + m)*4096;
  for (int idx=t; idx<4096; idx+=256){
    int i = idx>>6;
    cs[i][idx&63] = (cb[idx] + cb[idx+chs] + cb[idx+2*chs] + cb[idx+3*chs]) * invZ[i];
  }
  __syncthreads();
  for (int oo=0;oo<32;++oo){
    int o = z*128 + w*32 + oo;
    float acc = 0.f;
    #pragma unroll
    for (int j=0;j<64;++j) acc += wout[(size_t)o*CDIM + m*64 + j] * cs[l][j];
    weff[((size_t)b*CDIM + o)*CDIM + m*64 + l] = f2bf(acc);
  }
}

// ---- fused final GEMM + bias + channel-LN: 512(o) x 128(n) per block ----
__global__ __launch_bounds__(512) void k_out_ln(const unsigned short* __restrict__ Weff,
                                                const unsigned short* __restrict__ QT,
                                                const float* __restrict__ bias,
                                                const float* __restrict__ g,
                                                float* __restrict__ out){
  __shared__ unsigned short As[512*32];
  __shared__ unsigned short Bs[128*32];
  __shared__ float lnS[128], lnS2[128];
  int b = blockIdx.y, n0 = blockIdx.x*128;
  const unsigned short* Ab = Weff + (size_t)b*CDIM*CDIM;
  const unsigned short* Bb = QT + ((size_t)b*NSEQ + n0)*CDIM;
  int t = threadIdx.x, w = t>>6, l = t&63;
  int lr = l&15, kq = (l>>4)*8;
  int srow = t>>2, skc = (t&3)*8;
  const unsigned short* pA0 = Ab + (size_t)(srow      )*CDIM + skc;
  const unsigned short* pA1 = Ab + (size_t)(srow + 128)*CDIM + skc;
  const unsigned short* pA2 = Ab + (size_t)(srow + 256)*CDIM + skc;
  const unsigned short* pA3 = Ab + (size_t)(srow + 384)*CDIM + skc;
  const unsigned short* pB  = Bb + (size_t)(srow      )*CDIM + skc;
  char* dA = (char*)As + t*16;
  char* dB = (char*)Bs + t*16;
  f32x4 acc[4][8];
  #pragma unroll
  for (int mi=0;mi<4;mi++)
    #pragma unroll
    for (int ni=0;ni<8;ni++) acc[mi][ni] = (f32x4){0.f,0.f,0.f,0.f};
  for (int k0=0;k0<CDIM;k0+=32){
    gld_lds16(pA0, dA);
    gld_lds16(pA1, dA+8192);
    gld_lds16(pA2, dA+16384);
    gld_lds16(pA3, dA+24576);
    gld_lds16(pB,  dB);          // all 512 threads: Bs is 128 rows = 8192B = 512x16B
    __syncthreads();
    short8 af[4], bfv[8];
    #pragma unroll
    for (int mi=0;mi<4;mi++) af[mi]  = *(const short8*)&As[(w*64 + mi*16 + lr)*32 + kq];
    #pragma unroll
    for (int ni=0;ni<8;ni++) bfv[ni] = *(const short8*)&Bs[(ni*16 + lr)*32 + kq];
    #pragma unroll
    for (int mi=0;mi<4;mi++)
      #pragma unroll
      for (int ni=0;ni<8;ni++)
        acc[mi][ni] = __builtin_amdgcn_mfma_f32_16x16x32_bf16(af[mi], bfv[ni], acc[mi][ni], 0, 0, 0);
    __syncthreads();
    pA0 += 32; pA1 += 32; pA2 += 32; pA3 += 32; pB += 32;
  }
  if (t < 128){ lnS[t] = 0.f; lnS2[t] = 0.f; }
  __syncthreads();
  float ps[8], ps2[8];
  #pragma unroll
  for (int ni=0;ni<8;ni++){ ps[ni]=0.f; ps2[ni]=0.f; }
  #pragma unroll
  for (int mi=0;mi<4;mi++)
    #pragma unroll
    for (int r=0;r<4;r++){
      int row = w*64 + mi*16 + (l>>4)*4 + r;
      float bb = bias[row];
      #pragma unroll
      for (int ni=0;ni<8;ni++){
        float v = acc[mi][ni][r] + bb;
        acc[mi][ni][r] = v;
        ps[ni] += v; ps2[ni] += v*v;
      }
    }
  #pragma unroll
  for (int ni=0;ni<8;ni++){
    ps[ni]  += __shfl_xor(ps[ni], 16, 64);  ps[ni]  += __shfl_xor(ps[ni], 32, 64);
    ps2[ni] += __shfl_xor(ps2[ni], 16, 64); ps2[ni] += __shfl_xor(ps2[ni], 32, 64);
  }
  if ((l>>4) == 0){
    #pragma unroll
    for (int ni=0;ni<8;ni++){
      atomicAdd(&lnS[ni*16+lr],  ps[ni]);
      atomicAdd(&lnS2[ni*16+lr], ps2[ni]);
    }
  }
  __syncthreads();
  if (t < 128){
    float mean = lnS[t]*(1.f/512.f);
    float var  = lnS2[t]*(1.f/512.f) - mean*mean;
    lnS[t] = mean; lnS2[t] = rsqrtf(var + 1e-5f);
  }
  __syncthreads();
  float* ob = out + (size_t)b*CDIM*NSEQ + n0;
  #pragma unroll
  for (int ni=0;ni<8;ni++){
    int col = ni*16 + lr;
    float mean = lnS[col], rstd = lnS2[col];
    #pragma unroll
    for (int mi=0;mi<4;mi++)
      #pragma unroll
      for (int r=0;r<4;r++){
        int row = w*64 + mi*16 + (l>>4)*4 + r;
        ob[(size_t)row*NSEQ + col] = (acc[mi][ni][r] - mean)*rstd*g[row];
      }
  }
}

extern "C" void kernel_launch(void* const* d_in, const int* in_sizes, int n_in,
                              void* d_out, int out_size, void* d_ws, size_t ws_size,
                              hipStream_t stream){
  const float* x     = (const float*)d_in[0];
  const float* w_qkv = (const float*)d_in[1];
  const float* w_out = (const float*)d_in[2];
  const float* b_out = (const float*)d_in[3];
  const float* g_out = (const float*)d_in[4];
  float* out = (float*)d_out;
  char* ws = (char*)d_ws;

  size_t off = 0;
  unsigned short* wq_bf = (unsigned short*)(ws + off); off += (size_t)O3*CDIM*2;          // 1.5 MB
  char* xT_region = ws + off;                          off += (size_t)NB*NSEQ*CDIM*2;     // 67 MB
  unsigned short* qkv_kv = (unsigned short*)(ws + off); off += (size_t)NB*1024*NSEQ*2;    // 134 MB
  unsigned short* qsmT   = (unsigned short*)(ws + off); off += (size_t)NB*NSEQ*CDIM*2;    // 67 MB
  if (off > ws_size) return;
  unsigned short* xT = (unsigned short*)xT_region;
  // aliases into xT region (xT dead after both GEMMs):
  float* sump = (float*)(xT_region);                        // 128 KB
  float* ctx4 = (float*)(xT_region + (1<<20));              // 8 MB (4 chunks)
  unsigned short* weff = (unsigned short*)(xT_region + (16<<20)); // 8.4 MB

  k_conv_w     <<<O3*CDIM/1024, 256, 0, stream>>>(w_qkv, wq_bf);
  k_transpose_x<<<dim3(NSEQ/64, CDIM/64, NB), 256, 0, stream>>>(x, xT);
  k_gemm_kv    <<<dim3(NSEQ/128, 8, NB), 256, 0, stream>>>(wq_bf + (size_t)512*CDIM, xT, qkv_kv);
  k_gemm_q     <<<dim3(NSEQ/128, 4, NB), 256, 0, stream>>>(wq_bf, xT, qsmT);
  k_context    <<<dim3(NHEAD, NB, 4), 256, 0, stream>>>(qkv_kv, ctx4, sump);
  k_weff       <<<dim3(NHEAD, NB, 4), 256, 0, stream>>>(ctx4, sump, w_out, weff);
  k_out_ln     <<<dim3(NSEQ/128, NB), 512, 0, stream>>>(weff, qsmT, b_out, g_out, out);
}

// Round 11
// 385.402 us; speedup vs baseline: 1.0761x; 1.0761x over previous
//
#include <hip/hip_runtime.h>

#define NB 16
#define CDIM 512
#define NHEAD 8
#define DHEAD 64
#define NSEQ 4096
#define O3 1536

typedef __attribute__((ext_vector_type(8))) short short8;
typedef __attribute__((ext_vector_type(4))) float f32x4;
typedef __attribute__((ext_vector_type(4))) unsigned u32x4;
typedef __attribute__((ext_vector_type(2))) unsigned u32x2;
typedef __attribute__((ext_vector_type(4))) float fvec4;

__device__ __forceinline__ float bf2f(unsigned short u){
  union { unsigned u; float f; } v; v.u = ((unsigned)u) << 16; return v.f;
}
__device__ __forceinline__ unsigned short f2bf(float f){
  union { float f; unsigned u; } v; v.f = f;
  unsigned r = v.u + 0x7fffu + ((v.u >> 16) & 1u);
  return (unsigned short)(r >> 16);
}
__device__ __forceinline__ unsigned pack2(float a, float b){
  return (unsigned)f2bf(a) | ((unsigned)f2bf(b) << 16);
}
__device__ __forceinline__ void gld_lds16(const void* g, void* l){
  __builtin_amdgcn_global_load_lds(
      (const __attribute__((address_space(1))) unsigned*)g,
      (__attribute__((address_space(3))) unsigned*)l, 16, 0, 0);
}

// ---- w_qkv f32 -> bf16 ----
__global__ __launch_bounds__(256) void k_conv_w(const float* __restrict__ w,
                                                unsigned short* __restrict__ o){
  int i = (blockIdx.x*256 + threadIdx.x)*4;
  fvec4 v = *(const fvec4*)(w + i);
  u32x2 p; p[0] = pack2(v[0], v[1]); p[1] = pack2(v[2], v[3]);
  *(u32x2*)(o + i) = p;
}

// ---- x [b][c][n] f32 -> xT [b][n][c] bf16; 16B reads, 16B writes ----
__global__ __launch_bounds__(256) void k_transpose_x(const float* __restrict__ x,
                                                     unsigned short* __restrict__ xT){
  __shared__ unsigned short tile[64][65];
  int b = blockIdx.z, c0 = blockIdx.y*64, n0 = blockIdx.x*64;
  int t = threadIdx.x;
  const float* xb = x + ((size_t)b*CDIM + c0)*NSEQ + n0;
  #pragma unroll
  for (int i=0;i<4;i++){
    int idx = t + i*256;
    int r = idx>>4, c4 = (idx&15)*4;
    fvec4 v = *(const fvec4*)(xb + (size_t)r*NSEQ + c4);
    tile[r][c4]   = f2bf(v[0]);
    tile[r][c4+1] = f2bf(v[1]);
    tile[r][c4+2] = f2bf(v[2]);
    tile[r][c4+3] = f2bf(v[3]);
  }
  __syncthreads();
  unsigned short* ob = xT + ((size_t)b*NSEQ + n0)*CDIM + c0;
  #pragma unroll
  for (int i=0;i<2;i++){
    int chunk = t + i*256;
    int r = chunk>>3, c8 = (chunk&7)*8;
    u32x4 p;
    #pragma unroll
    for (int k=0;k<4;k++)
      p[k] = (unsigned)tile[c8+2*k][r] | ((unsigned)tile[c8+2*k+1][r] << 16);
    *(u32x4*)(ob + (size_t)r*CDIM + c8) = p;
  }
}

// ---- k/v GEMM: r6 BK=64 split-half body (inline staging addresses).
//      k-tiles (o0<512) write bf16(exp(k)); v-tiles write raw bf16. ----
__global__ __launch_bounds__(256) void k_gemm_kv(const unsigned short* __restrict__ A,
                                                 const unsigned short* __restrict__ Bt,
                                                 unsigned short* __restrict__ KV){
  __shared__ unsigned short As[2][128*32];   // 16 KB
  __shared__ unsigned short Bs[2][128*32];   // 16 KB
  int b = blockIdx.z;
  int n0 = blockIdx.x*128, o0 = blockIdx.y*128;
  const unsigned short* Bb = Bt + (size_t)b*NSEQ*CDIM;
  unsigned short* Cb = KV + (size_t)b*1024*NSEQ;
  int t = threadIdx.x, w = t>>6, l = t&63;
  int lr = l&15, kq = (l>>4)*8;
  int wr = (w>>1)*64, wc = (w&1)*64;
  f32x4 acc[4][4];
  #pragma unroll
  for (int mi=0;mi<4;mi++)
    #pragma unroll
    for (int ni=0;ni<4;ni++) acc[mi][ni] = (f32x4){0.f,0.f,0.f,0.f};
  for (int k0=0;k0<CDIM;k0+=64){
    #pragma unroll
    for (int h=0;h<2;++h){
      #pragma unroll
      for (int it=0;it<2;++it){
        int chunk = it*256 + t;
        int row = chunk>>2, kc = (chunk&3)*8;
        gld_lds16(A  + (size_t)(o0+row)*CDIM + k0 + h*32 + kc, (char*)As[h] + (size_t)chunk*16);
        gld_lds16(Bb + (size_t)(n0+row)*CDIM + k0 + h*32 + kc, (char*)Bs[h] + (size_t)chunk*16);
      }
    }
    __syncthreads();
    #pragma unroll
    for (int h=0;h<2;++h){
      short8 af[4], bfv[4];
      #pragma unroll
      for (int mi=0;mi<4;mi++) af[mi]  = *(const short8*)&As[h][(wr + mi*16 + lr)*32 + kq];
      #pragma unroll
      for (int ni=0;ni<4;ni++) bfv[ni] = *(const short8*)&Bs[h][(wc + ni*16 + lr)*32 + kq];
      #pragma unroll
      for (int mi=0;mi<4;mi++)
        #pragma unroll
        for (int ni=0;ni<4;ni++)
          acc[mi][ni] = __builtin_amdgcn_mfma_f32_16x16x32_bf16(af[mi], bfv[ni], acc[mi][ni], 0, 0, 0);
    }
    __syncthreads();
  }
  if (o0 < 512){   // k channels: fuse exp
    #pragma unroll
    for (int mi=0;mi<4;mi++)
      #pragma unroll
      for (int ni=0;ni<4;ni++)
        #pragma unroll
        for (int r=0;r<4;r++){
          int row = o0 + wr + mi*16 + (l>>4)*4 + r;
          int col = n0 + wc + ni*16 + lr;
          Cb[(size_t)row*NSEQ + col] = f2bf(__expf(acc[mi][ni][r]));
        }
  } else {
    #pragma unroll
    for (int mi=0;mi<4;mi++)
      #pragma unroll
      for (int ni=0;ni<4;ni++)
        #pragma unroll
        for (int r=0;r<4;r++){
          int row = o0 + wr + mi*16 + (l>>4)*4 + r;
          int col = n0 + wc + ni*16 + lr;
          Cb[(size_t)row*NSEQ + col] = f2bf(acc[mi][ni][r]);
        }
  }
}

// ---- q GEMM (r6 BK=64 split halves, inline staging) + in-reg softmax ----
#define TS 136
__global__ __launch_bounds__(256) void k_gemm_q(const unsigned short* __restrict__ A,
                                                const unsigned short* __restrict__ Bt,
                                                unsigned short* __restrict__ qsmT){
  __shared__ unsigned short smem[128*128];   // 32 KB: 4x 128x32 halves; epilogue tile aliases
  int b = blockIdx.z;
  int n0 = blockIdx.x*128, o0 = blockIdx.y*128;
  const unsigned short* Bb = Bt + (size_t)b*NSEQ*CDIM;
  int t = threadIdx.x, w = t>>6, l = t&63;
  int lr = l&15, kq = (l>>4)*8;
  int wr = (w>>1)*64, wc = (w&1)*64;
  f32x4 acc[4][4];
  #pragma unroll
  for (int mi=0;mi<4;mi++)
    #pragma unroll
    for (int ni=0;ni<4;ni++) acc[mi][ni] = (f32x4){0.f,0.f,0.f,0.f};
  for (int k0=0;k0<CDIM;k0+=64){
    #pragma unroll
    for (int h=0;h<2;++h){
      unsigned short* Ash = smem + h*4096;
      unsigned short* Bsh = smem + 8192 + h*4096;
      #pragma unroll
      for (int it=0;it<2;++it){
        int chunk = it*256 + t;
        int row = chunk>>2, kc = (chunk&3)*8;
        gld_lds16(A  + (size_t)(o0+row)*CDIM + k0 + h*32 + kc, (char*)Ash + (size_t)chunk*16);
        gld_lds16(Bb + (size_t)(n0+row)*CDIM + k0 + h*32 + kc, (char*)Bsh + (size_t)chunk*16);
      }
    }
    __syncthreads();
    #pragma unroll
    for (int h=0;h<2;++h){
      const unsigned short* Ash = smem + h*4096;
      const unsigned short* Bsh = smem + 8192 + h*4096;
      short8 af[4], bfv[4];
      #pragma unroll
      for (int mi=0;mi<4;mi++) af[mi]  = *(const short8*)&Ash[(wr + mi*16 + lr)*32 + kq];
      #pragma unroll
      for (int ni=0;ni<4;ni++) bfv[ni] = *(const short8*)&Bsh[(wc + ni*16 + lr)*32 + kq];
      #pragma unroll
      for (int mi=0;mi<4;mi++)
        #pragma unroll
        for (int ni=0;ni<4;ni++)
          acc[mi][ni] = __builtin_amdgcn_mfma_f32_16x16x32_bf16(af[mi], bfv[ni], acc[mi][ni], 0, 0, 0);
    }
    __syncthreads();
  }
  // in-register softmax over d (wave's 64 rows = one head) per column
  unsigned pk[4][4][2];
  #pragma unroll
  for (int ni=0;ni<4;ni++){
    float mx = -1e30f;
    #pragma unroll
    for (int mi=0;mi<4;mi++)
      #pragma unroll
      for (int r=0;r<4;r++) mx = fmaxf(mx, acc[mi][ni][r]);
    mx = fmaxf(mx, __shfl_xor(mx, 16, 64));
    mx = fmaxf(mx, __shfl_xor(mx, 32, 64));
    float s = 0.f;
    #pragma unroll
    for (int mi=0;mi<4;mi++)
      #pragma unroll
      for (int r=0;r<4;r++){
        float p = __expf(acc[mi][ni][r] - mx);
        acc[mi][ni][r] = p; s += p;
      }
    s += __shfl_xor(s, 16, 64);
    s += __shfl_xor(s, 32, 64);
    float inv = 0.125f / s;
    #pragma unroll
    for (int mi=0;mi<4;mi++){
      pk[mi][ni][0] = pack2(acc[mi][ni][0]*inv, acc[mi][ni][1]*inv);
      pk[mi][ni][1] = pack2(acc[mi][ni][2]*inv, acc[mi][ni][3]*inv);
    }
  }
  #pragma unroll
  for (int ck=0;ck<2;++ck){
    if ((w&1) == ck){
      #pragma unroll
      for (int mi=0;mi<4;mi++)
        #pragma unroll
        for (int ni=0;ni<4;ni++){
          int idx = (ni*16 + lr)*TS + wr + mi*16 + (l>>4)*4;
          u32x2 p; p[0] = pk[mi][ni][0]; p[1] = pk[mi][ni][1];
          *(u32x2*)&smem[idx] = p;
        }
    }
    __syncthreads();
    int col = t>>2, rs = (t&3)*32;
    unsigned short* dst = qsmT + ((size_t)b*NSEQ + n0 + ck*64 + col)*CDIM + o0 + rs;
    #pragma unroll
    for (int j=0;j<4;++j)
      *(u32x4*)(dst + j*8) = *(const u32x4*)&smem[col*TS + rs + j*8];
    __syncthreads();
  }
}

// ---- partial context over n-chunk; k already holds bf16(exp(k)) ----
__global__ __launch_bounds__(256) void k_context(const unsigned short* __restrict__ KV,
                                                 float* __restrict__ ctx4,
                                                 float* __restrict__ sump){
  __shared__ unsigned short Vs[64*64];
  int m = blockIdx.x, b = blockIdx.y, ch = blockIdx.z;
  int t = threadIdx.x, w = t>>6, l = t&63;
  int lr = l&15, kq = (l>>4)*8;
  const unsigned short* kbase = KV + ((size_t)b*1024 + m*64)*NSEQ;
  const unsigned short* vbase = KV + ((size_t)b*1024 + 512 + m*64)*NSEQ;
  int irow = w*16 + lr;
  int sub = l>>4;
  int nbeg = ch*1024;
  float rsum = 0.f;
  f32x4 acc[4];
  #pragma unroll
  for (int jf=0;jf<4;++jf) acc[jf] = (f32x4){0.f,0.f,0.f,0.f};
  for (int n0=nbeg;n0<nbeg+1024;n0+=64){
    #pragma unroll
    for (int it=0;it<2;++it){
      int chunk = it*256 + t;
      int row = chunk>>3, kc = (chunk&7)*8;
      gld_lds16(vbase + (size_t)row*NSEQ + n0 + kc, (char*)Vs + (size_t)chunk*16);
    }
    __syncthreads();
    #pragma unroll
    for (int kk=0;kk<2;++kk){
      u32x4 kraw = *(const u32x4*)(kbase + (size_t)irow*NSEQ + n0 + kk*32 + kq);
      short8 af = *(const short8*)&kraw;        // bit-identical: values are exp(k) bf16
      #pragma unroll
      for (int c=0;c<4;++c){
        unsigned u = kraw[c];
        rsum += bf2f((unsigned short)u) + bf2f((unsigned short)(u>>16));
      }
      #pragma unroll
      for (int jf=0;jf<4;++jf){
        short8 bv = *(const short8*)&Vs[(jf*16+lr)*64 + kk*32 + kq];
        acc[jf] = __builtin_amdgcn_mfma_f32_16x16x32_bf16(af, bv, acc[jf], 0, 0, 0);
      }
    }
    __syncthreads();
  }
  rsum += __shfl_xor(rsum, 16, 64);
  rsum += __shfl_xor(rsum, 32, 64);
  size_t sbase = (((size_t)ch*NB + b)*NHEAD + m)*64;
  if (sub == 0) sump[sbase + irow] = rsum;
  float* cb = ctx4 + (((size_t)ch*NB + b)*NHEAD + m)*4096;
  #pragma unroll
  for (int jf=0;jf<4;++jf)
    #pragma unroll
    for (int r=0;r<4;++r){
      int i = w*16 + (l>>4)*4 + r;
      int j = jf*16 + lr;
      cb[i*64 + j] = acc[jf][r];
    }
}

// ---- W_eff: plain-sum merge of 4 chunk-partials, then fold w_out ----
__global__ __launch_bounds__(256) void k_weff(const float* __restrict__ ctx4,
                                              const float* __restrict__ sump,
                                              const float* __restrict__ wout,
                                              unsigned short* __restrict__ weff){
  __shared__ float cs[64][65];
  __shared__ float invZ[64];
  int m = blockIdx.x, b = blockIdx.y, z = blockIdx.z;
  int t = threadIdx.x, w = t>>6, l = t&63;
  const size_t chs = (size_t)NB*NHEAD*4096;
  const size_t sts = (size_t)NB*NHEAD*64;
  size_t sb = ((size_t)b*NHEAD + m)*64;
  if (t < 64){
    float Z = sump[sb + t] + sump[sb + sts + t]
            + sump[sb + 2*sts + t] + sump[sb + 3*sts + t];
    invZ[t] = 1.f/Z;
  }
  __syncthreads();
  const float* cb = ctx4 + ((size_t)b*NHEAD + m)*4096;
  for (int idx=t; idx<4096; idx+=256){
    int i = idx>>6;
    cs[i][idx&63] = (cb[idx] + cb[idx+chs] + cb[idx+2*chs] + cb[idx+3*chs]) * invZ[i];
  }
  __syncthreads();
  for (int oo=0;oo<32;++oo){
    int o = z*128 + w*32 + oo;
    float acc = 0.f;
    #pragma unroll
    for (int j=0;j<64;++j) acc += wout[(size_t)o*CDIM + m*64 + j] * cs[l][j];
    weff[((size_t)b*CDIM + o)*CDIM + m*64 + l] = f2bf(acc);
  }
}

// ---- fused final GEMM + bias + channel-LN: 512(o) x 128(n) per block ----
__global__ __launch_bounds__(512) void k_out_ln(const unsigned short* __restrict__ Weff,
                                                const unsigned short* __restrict__ QT,
                                                const float* __restrict__ bias,
                                                const float* __restrict__ g,
                                                float* __restrict__ out){
  __shared__ unsigned short As[512*32];
  __shared__ unsigned short Bs[128*32];
  __shared__ float lnS[128], lnS2[128];
  int b = blockIdx.y, n0 = blockIdx.x*128;
  const unsigned short* Ab = Weff + (size_t)b*CDIM*CDIM;
  const unsigned short* Bb = QT + ((size_t)b*NSEQ + n0)*CDIM;
  int t = threadIdx.x, w = t>>6, l = t&63;
  int lr = l&15, kq = (l>>4)*8;
  f32x4 acc[4][8];
  #pragma unroll
  for (int mi=0;mi<4;mi++)
    #pragma unroll
    for (int ni=0;ni<8;ni++) acc[mi][ni] = (f32x4){0.f,0.f,0.f,0.f};
  for (int k0=0;k0<CDIM;k0+=32){
    #pragma unroll
    for (int it=0;it<4;++it){
      int chunk = it*512 + t;
      int row = chunk>>2, kc = (chunk&3)*8;
      gld_lds16(Ab + (size_t)row*CDIM + k0 + kc, (char*)As + (size_t)chunk*16);
    }
    {
      int row = t>>2, kc = (t&3)*8;
      gld_lds16(Bb + (size_t)row*CDIM + k0 + kc, (char*)Bs + (size_t)t*16);
    }
    __syncthreads();
    short8 af[4], bfv[8];
    #pragma unroll
    for (int mi=0;mi<4;mi++) af[mi]  = *(const short8*)&As[(w*64 + mi*16 + lr)*32 + kq];
    #pragma unroll
    for (int ni=0;ni<8;ni++) bfv[ni] = *(const short8*)&Bs[(ni*16 + lr)*32 + kq];
    #pragma unroll
    for (int mi=0;mi<4;mi++)
      #pragma unroll
      for (int ni=0;ni<8;ni++)
        acc[mi][ni] = __builtin_amdgcn_mfma_f32_16x16x32_bf16(af[mi], bfv[ni], acc[mi][ni], 0, 0, 0);
    __syncthreads();
  }
  if (t < 128){ lnS[t] = 0.f; lnS2[t] = 0.f; }
  __syncthreads();
  float ps[8], ps2[8];
  #pragma unroll
  for (int ni=0;ni<8;ni++){ ps[ni]=0.f; ps2[ni]=0.f; }
  #pragma unroll
  for (int mi=0;mi<4;mi++)
    #pragma unroll
    for (int r=0;r<4;r++){
      int row = w*64 + mi*16 + (l>>4)*4 + r;
      float bb = bias[row];
      #pragma unroll
      for (int ni=0;ni<8;ni++){
        float v = acc[mi][ni][r] + bb;
        acc[mi][ni][r] = v;
        ps[ni] += v; ps2[ni] += v*v;
      }
    }
  #pragma unroll
  for (int ni=0;ni<8;ni++){
    ps[ni]  += __shfl_xor(ps[ni], 16, 64);  ps[ni]  += __shfl_xor(ps[ni], 32, 64);
    ps2[ni] += __shfl_xor(ps2[ni], 16, 64); ps2[ni] += __shfl_xor(ps2[ni], 32, 64);
  }
  if ((l>>4) == 0){
    #pragma unroll
    for (int ni=0;ni<8;ni++){
      atomicAdd(&lnS[ni*16+lr],  ps[ni]);
      atomicAdd(&lnS2[ni*16+lr], ps2[ni]);
    }
  }
  __syncthreads();
  if (t < 128){
    float mean = lnS[t]*(1.f/512.f);
    float var  = lnS2[t]*(1.f/512.f) - mean*mean;
    lnS[t] = mean; lnS2[t] = rsqrtf(var + 1e-5f);
  }
  __syncthreads();
  float* ob = out + (size_t)b*CDIM*NSEQ + n0;
  #pragma unroll
  for (int ni=0;ni<8;ni++){
    int col = ni*16 + lr;
    float mean = lnS[col], rstd = lnS2[col];
    #pragma unroll
    for (int mi=0;mi<4;mi++)
      #pragma unroll
      for (int r=0;r<4;r++){
        int row = w*64 + mi*16 + (l>>4)*4 + r;
        ob[(size_t)row*NSEQ + col] = (acc[mi][ni][r] - mean)*rstd*g[row];
      }
  }
}

extern "C" void kernel_launch(void* const* d_in, const int* in_sizes, int n_in,
                              void* d_out, int out_size, void* d_ws, size_t ws_size,
                              hipStream_t stream){
  const float* x     = (const float*)d_in[0];
  const float* w_qkv = (const float*)d_in[1];
  const float* w_out = (const float*)d_in[2];
  const float* b_out = (const float*)d_in[3];
  const float* g_out = (const float*)d_in[4];
  float* out = (float*)d_out;
  char* ws = (char*)d_ws;

  size_t off = 0;
  unsigned short* wq_bf = (unsigned short*)(ws + off); off += (size_t)O3*CDIM*2;          // 1.5 MB
  char* xT_region = ws + off;                          off += (size_t)NB*NSEQ*CDIM*2;     // 67 MB
  unsigned short* qkv_kv = (unsigned short*)(ws + off); off += (size_t)NB*1024*NSEQ*2;    // 134 MB
  unsigned short* qsmT   = (unsigned short*)(ws + off); off += (size_t)NB*NSEQ*CDIM*2;    // 67 MB
  if (off > ws_size) return;
  unsigned short* xT = (unsigned short*)xT_region;
  // aliases into xT region (xT dead after both GEMMs):
  float* sump = (float*)(xT_region);                        // 128 KB
  float* ctx4 = (float*)(xT_region + (1<<20));              // 8 MB (4 chunks)
  unsigned short* weff = (unsigned short*)(xT_region + (16<<20)); // 8.4 MB

  k_conv_w     <<<O3*CDIM/1024, 256, 0, stream>>>(w_qkv, wq_bf);
  k_transpose_x<<<dim3(NSEQ/64, CDIM/64, NB), 256, 0, stream>>>(x, xT);
  k_gemm_kv    <<<dim3(NSEQ/128, 8, NB), 256, 0, stream>>>(wq_bf + (size_t)512*CDIM, xT, qkv_kv);
  k_gemm_q     <<<dim3(NSEQ/128, 4, NB), 256, 0, stream>>>(wq_bf, xT, qsmT);
  k_context    <<<dim3(NHEAD, NB, 4), 256, 0, stream>>>(qkv_kv, ctx4, sump);
  k_weff       <<<dim3(NHEAD, NB, 4), 256, 0, stream>>>(ctx4, sump, w_out, weff);
  k_out_ln     <<<dim3(NSEQ/128, NB), 512, 0, stream>>>(weff, qsmT, b_out, g_out, out);
}

// Round 12
// 379.854 us; speedup vs baseline: 1.0919x; 1.0146x over previous
//
#include <hip/hip_runtime.h>

#define NB 16
#define CDIM 512
#define NHEAD 8
#define DHEAD 64
#define NSEQ 4096
#define O3 1536

typedef __attribute__((ext_vector_type(8))) short short8;
typedef __attribute__((ext_vector_type(4))) float f32x4;
typedef __attribute__((ext_vector_type(4))) unsigned u32x4;
typedef __attribute__((ext_vector_type(2))) unsigned u32x2;
typedef __attribute__((ext_vector_type(4))) float fvec4;

__device__ __forceinline__ float bf2f(unsigned short u){
  union { unsigned u; float f; } v; v.u = ((unsigned)u) << 16; return v.f;
}
__device__ __forceinline__ unsigned short f2bf(float f){
  union { float f; unsigned u; } v; v.f = f;
  unsigned r = v.u + 0x7fffu + ((v.u >> 16) & 1u);
  return (unsigned short)(r >> 16);
}
__device__ __forceinline__ unsigned pack2(float a, float b){
  return (unsigned)f2bf(a) | ((unsigned)f2bf(b) << 16);
}
__device__ __forceinline__ void gld_lds16(const void* g, void* l){
  __builtin_amdgcn_global_load_lds(
      (const __attribute__((address_space(1))) unsigned*)g,
      (__attribute__((address_space(3))) unsigned*)l, 16, 0, 0);
}

// ---- w_qkv f32 -> bf16 ----
__global__ __launch_bounds__(256) void k_conv_w(const float* __restrict__ w,
                                                unsigned short* __restrict__ o){
  int i = (blockIdx.x*256 + threadIdx.x)*4;
  fvec4 v = *(const fvec4*)(w + i);
  u32x2 p; p[0] = pack2(v[0], v[1]); p[1] = pack2(v[2], v[3]);
  *(u32x2*)(o + i) = p;
}

// ---- x [b][c][n] f32 -> xT [b][n][c] bf16; 16B reads, 16B writes ----
__global__ __launch_bounds__(256) void k_transpose_x(const float* __restrict__ x,
                                                     unsigned short* __restrict__ xT){
  __shared__ unsigned short tile[64][65];
  int b = blockIdx.z, c0 = blockIdx.y*64, n0 = blockIdx.x*64;
  int t = threadIdx.x;
  const float* xb = x + ((size_t)b*CDIM + c0)*NSEQ + n0;
  #pragma unroll
  for (int i=0;i<4;i++){
    int idx = t + i*256;
    int r = idx>>4, c4 = (idx&15)*4;
    fvec4 v = *(const fvec4*)(xb + (size_t)r*NSEQ + c4);
    tile[r][c4]   = f2bf(v[0]);
    tile[r][c4+1] = f2bf(v[1]);
    tile[r][c4+2] = f2bf(v[2]);
    tile[r][c4+3] = f2bf(v[3]);
  }
  __syncthreads();
  unsigned short* ob = xT + ((size_t)b*NSEQ + n0)*CDIM + c0;
  #pragma unroll
  for (int i=0;i<2;i++){
    int chunk = t + i*256;
    int r = chunk>>3, c8 = (chunk&7)*8;
    u32x4 p;
    #pragma unroll
    for (int k=0;k<4;k++)
      p[k] = (unsigned)tile[c8+2*k][r] | ((unsigned)tile[c8+2*k+1][r] << 16);
    *(u32x4*)(ob + (size_t)r*CDIM + c8) = p;
  }
}

// ---- k GEMM: r6 BK=64 split-half body, uniform exp epilogue -> KV rows 0-511 ----
__global__ __launch_bounds__(256) void k_gemm_k(const unsigned short* __restrict__ A,
                                                const unsigned short* __restrict__ Bt,
                                                unsigned short* __restrict__ KV){
  __shared__ unsigned short As[2][128*32];
  __shared__ unsigned short Bs[2][128*32];
  int b = blockIdx.z;
  int n0 = blockIdx.x*128, o0 = blockIdx.y*128;
  const unsigned short* Bb = Bt + (size_t)b*NSEQ*CDIM;
  unsigned short* Cb = KV + (size_t)b*1024*NSEQ;
  int t = threadIdx.x, w = t>>6, l = t&63;
  int lr = l&15, kq = (l>>4)*8;
  int wr = (w>>1)*64, wc = (w&1)*64;
  f32x4 acc[4][4];
  #pragma unroll
  for (int mi=0;mi<4;mi++)
    #pragma unroll
    for (int ni=0;ni<4;ni++) acc[mi][ni] = (f32x4){0.f,0.f,0.f,0.f};
  for (int k0=0;k0<CDIM;k0+=64){
    #pragma unroll
    for (int h=0;h<2;++h){
      #pragma unroll
      for (int it=0;it<2;++it){
        int chunk = it*256 + t;
        int row = chunk>>2, kc = (chunk&3)*8;
        gld_lds16(A  + (size_t)(o0+row)*CDIM + k0 + h*32 + kc, (char*)As[h] + (size_t)chunk*16);
        gld_lds16(Bb + (size_t)(n0+row)*CDIM + k0 + h*32 + kc, (char*)Bs[h] + (size_t)chunk*16);
      }
    }
    __syncthreads();
    #pragma unroll
    for (int h=0;h<2;++h){
      short8 af[4], bfv[4];
      #pragma unroll
      for (int mi=0;mi<4;mi++) af[mi]  = *(const short8*)&As[h][(wr + mi*16 + lr)*32 + kq];
      #pragma unroll
      for (int ni=0;ni<4;ni++) bfv[ni] = *(const short8*)&Bs[h][(wc + ni*16 + lr)*32 + kq];
      #pragma unroll
      for (int mi=0;mi<4;mi++)
        #pragma unroll
        for (int ni=0;ni<4;ni++)
          acc[mi][ni] = __builtin_amdgcn_mfma_f32_16x16x32_bf16(af[mi], bfv[ni], acc[mi][ni], 0, 0, 0);
    }
    __syncthreads();
  }
  #pragma unroll
  for (int mi=0;mi<4;mi++)
    #pragma unroll
    for (int ni=0;ni<4;ni++)
      #pragma unroll
      for (int r=0;r<4;r++){
        int row = o0 + wr + mi*16 + (l>>4)*4 + r;
        int col = n0 + wc + ni*16 + lr;
        Cb[(size_t)row*NSEQ + col] = f2bf(__expf(acc[mi][ni][r]));
      }
}

// ---- v GEMM: r6 BK=64 split-half body, plain epilogue -> KV rows 512-1023 ----
__global__ __launch_bounds__(256) void k_gemm_v(const unsigned short* __restrict__ A,
                                                const unsigned short* __restrict__ Bt,
                                                unsigned short* __restrict__ KV){
  __shared__ unsigned short As[2][128*32];
  __shared__ unsigned short Bs[2][128*32];
  int b = blockIdx.z;
  int n0 = blockIdx.x*128, o0 = blockIdx.y*128;
  const unsigned short* Bb = Bt + (size_t)b*NSEQ*CDIM;
  unsigned short* Cb = KV + (size_t)b*1024*NSEQ + (size_t)512*NSEQ;
  int t = threadIdx.x, w = t>>6, l = t&63;
  int lr = l&15, kq = (l>>4)*8;
  int wr = (w>>1)*64, wc = (w&1)*64;
  f32x4 acc[4][4];
  #pragma unroll
  for (int mi=0;mi<4;mi++)
    #pragma unroll
    for (int ni=0;ni<4;ni++) acc[mi][ni] = (f32x4){0.f,0.f,0.f,0.f};
  for (int k0=0;k0<CDIM;k0+=64){
    #pragma unroll
    for (int h=0;h<2;++h){
      #pragma unroll
      for (int it=0;it<2;++it){
        int chunk = it*256 + t;
        int row = chunk>>2, kc = (chunk&3)*8;
        gld_lds16(A  + (size_t)(o0+row)*CDIM + k0 + h*32 + kc, (char*)As[h] + (size_t)chunk*16);
        gld_lds16(Bb + (size_t)(n0+row)*CDIM + k0 + h*32 + kc, (char*)Bs[h] + (size_t)chunk*16);
      }
    }
    __syncthreads();
    #pragma unroll
    for (int h=0;h<2;++h){
      short8 af[4], bfv[4];
      #pragma unroll
      for (int mi=0;mi<4;mi++) af[mi]  = *(const short8*)&As[h][(wr + mi*16 + lr)*32 + kq];
      #pragma unroll
      for (int ni=0;ni<4;ni++) bfv[ni] = *(const short8*)&Bs[h][(wc + ni*16 + lr)*32 + kq];
      #pragma unroll
      for (int mi=0;mi<4;mi++)
        #pragma unroll
        for (int ni=0;ni<4;ni++)
          acc[mi][ni] = __builtin_amdgcn_mfma_f32_16x16x32_bf16(af[mi], bfv[ni], acc[mi][ni], 0, 0, 0);
    }
    __syncthreads();
  }
  #pragma unroll
  for (int mi=0;mi<4;mi++)
    #pragma unroll
    for (int ni=0;ni<4;ni++)
      #pragma unroll
      for (int r=0;r<4;r++){
        int row = o0 + wr + mi*16 + (l>>4)*4 + r;
        int col = n0 + wc + ni*16 + lr;
        Cb[(size_t)row*NSEQ + col] = f2bf(acc[mi][ni][r]);
      }
}

// ---- q GEMM (r6 BK=64 split halves, inline staging) + in-reg softmax ----
#define TS 136
__global__ __launch_bounds__(256) void k_gemm_q(const unsigned short* __restrict__ A,
                                                const unsigned short* __restrict__ Bt,
                                                unsigned short* __restrict__ qsmT){
  __shared__ unsigned short smem[128*128];   // 32 KB: 4x 128x32 halves; epilogue tile aliases
  int b = blockIdx.z;
  int n0 = blockIdx.x*128, o0 = blockIdx.y*128;
  const unsigned short* Bb = Bt + (size_t)b*NSEQ*CDIM;
  int t = threadIdx.x, w = t>>6, l = t&63;
  int lr = l&15, kq = (l>>4)*8;
  int wr = (w>>1)*64, wc = (w&1)*64;
  f32x4 acc[4][4];
  #pragma unroll
  for (int mi=0;mi<4;mi++)
    #pragma unroll
    for (int ni=0;ni<4;ni++) acc[mi][ni] = (f32x4){0.f,0.f,0.f,0.f};
  for (int k0=0;k0<CDIM;k0+=64){
    #pragma unroll
    for (int h=0;h<2;++h){
      unsigned short* Ash = smem + h*4096;
      unsigned short* Bsh = smem + 8192 + h*4096;
      #pragma unroll
      for (int it=0;it<2;++it){
        int chunk = it*256 + t;
        int row = chunk>>2, kc = (chunk&3)*8;
        gld_lds16(A  + (size_t)(o0+row)*CDIM + k0 + h*32 + kc, (char*)Ash + (size_t)chunk*16);
        gld_lds16(Bb + (size_t)(n0+row)*CDIM + k0 + h*32 + kc, (char*)Bsh + (size_t)chunk*16);
      }
    }
    __syncthreads();
    #pragma unroll
    for (int h=0;h<2;++h){
      const unsigned short* Ash = smem + h*4096;
      const unsigned short* Bsh = smem + 8192 + h*4096;
      short8 af[4], bfv[4];
      #pragma unroll
      for (int mi=0;mi<4;mi++) af[mi]  = *(const short8*)&Ash[(wr + mi*16 + lr)*32 + kq];
      #pragma unroll
      for (int ni=0;ni<4;ni++) bfv[ni] = *(const short8*)&Bsh[(wc + ni*16 + lr)*32 + kq];
      #pragma unroll
      for (int mi=0;mi<4;mi++)
        #pragma unroll
        for (int ni=0;ni<4;ni++)
          acc[mi][ni] = __builtin_amdgcn_mfma_f32_16x16x32_bf16(af[mi], bfv[ni], acc[mi][ni], 0, 0, 0);
    }
    __syncthreads();
  }
  // in-register softmax over d (wave's 64 rows = one head) per column
  unsigned pk[4][4][2];
  #pragma unroll
  for (int ni=0;ni<4;ni++){
    float mx = -1e30f;
    #pragma unroll
    for (int mi=0;mi<4;mi++)
      #pragma unroll
      for (int r=0;r<4;r++) mx = fmaxf(mx, acc[mi][ni][r]);
    mx = fmaxf(mx, __shfl_xor(mx, 16, 64));
    mx = fmaxf(mx, __shfl_xor(mx, 32, 64));
    float s = 0.f;
    #pragma unroll
    for (int mi=0;mi<4;mi++)
      #pragma unroll
      for (int r=0;r<4;r++){
        float p = __expf(acc[mi][ni][r] - mx);
        acc[mi][ni][r] = p; s += p;
      }
    s += __shfl_xor(s, 16, 64);
    s += __shfl_xor(s, 32, 64);
    float inv = 0.125f / s;
    #pragma unroll
    for (int mi=0;mi<4;mi++){
      pk[mi][ni][0] = pack2(acc[mi][ni][0]*inv, acc[mi][ni][1]*inv);
      pk[mi][ni][1] = pack2(acc[mi][ni][2]*inv, acc[mi][ni][3]*inv);
    }
  }
  #pragma unroll
  for (int ck=0;ck<2;++ck){
    if ((w&1) == ck){
      #pragma unroll
      for (int mi=0;mi<4;mi++)
        #pragma unroll
        for (int ni=0;ni<4;ni++){
          int idx = (ni*16 + lr)*TS + wr + mi*16 + (l>>4)*4;
          u32x2 p; p[0] = pk[mi][ni][0]; p[1] = pk[mi][ni][1];
          *(u32x2*)&smem[idx] = p;
        }
    }
    __syncthreads();
    int col = t>>2, rs = (t&3)*32;
    unsigned short* dst = qsmT + ((size_t)b*NSEQ + n0 + ck*64 + col)*CDIM + o0 + rs;
    #pragma unroll
    for (int j=0;j<4;++j)
      *(u32x4*)(dst + j*8) = *(const u32x4*)&smem[col*TS + rs + j*8];
    __syncthreads();
  }
}

// ---- partial context over n-chunk; k already holds bf16(exp(k)) ----
__global__ __launch_bounds__(256) void k_context(const unsigned short* __restrict__ KV,
                                                 float* __restrict__ ctx4,
                                                 float* __restrict__ sump){
  __shared__ unsigned short Vs[64*64];
  int m = blockIdx.x, b = blockIdx.y, ch = blockIdx.z;
  int t = threadIdx.x, w = t>>6, l = t&63;
  int lr = l&15, kq = (l>>4)*8;
  const unsigned short* kbase = KV + ((size_t)b*1024 + m*64)*NSEQ;
  const unsigned short* vbase = KV + ((size_t)b*1024 + 512 + m*64)*NSEQ;
  int irow = w*16 + lr;
  int sub = l>>4;
  int nbeg = ch*1024;
  float rsum = 0.f;
  f32x4 acc[4];
  #pragma unroll
  for (int jf=0;jf<4;++jf) acc[jf] = (f32x4){0.f,0.f,0.f,0.f};
  for (int n0=nbeg;n0<nbeg+1024;n0+=64){
    #pragma unroll
    for (int it=0;it<2;++it){
      int chunk = it*256 + t;
      int row = chunk>>3, kc = (chunk&7)*8;
      gld_lds16(vbase + (size_t)row*NSEQ + n0 + kc, (char*)Vs + (size_t)chunk*16);
    }
    __syncthreads();
    #pragma unroll
    for (int kk=0;kk<2;++kk){
      u32x4 kraw = *(const u32x4*)(kbase + (size_t)irow*NSEQ + n0 + kk*32 + kq);
      short8 af = *(const short8*)&kraw;        // bit-identical: values are exp(k) bf16
      #pragma unroll
      for (int c=0;c<4;++c){
        unsigned u = kraw[c];
        rsum += bf2f((unsigned short)u) + bf2f((unsigned short)(u>>16));
      }
      #pragma unroll
      for (int jf=0;jf<4;++jf){
        short8 bv = *(const short8*)&Vs[(jf*16+lr)*64 + kk*32 + kq];
        acc[jf] = __builtin_amdgcn_mfma_f32_16x16x32_bf16(af, bv, acc[jf], 0, 0, 0);
      }
    }
    __syncthreads();
  }
  rsum += __shfl_xor(rsum, 16, 64);
  rsum += __shfl_xor(rsum, 32, 64);
  size_t sbase = (((size_t)ch*NB + b)*NHEAD + m)*64;
  if (sub == 0) sump[sbase + irow] = rsum;
  float* cb = ctx4 + (((size_t)ch*NB + b)*NHEAD + m)*4096;
  #pragma unroll
  for (int jf=0;jf<4;++jf)
    #pragma unroll
    for (int r=0;r<4;++r){
      int i = w*16 + (l>>4)*4 + r;
      int j = jf*16 + lr;
      cb[i*64 + j] = acc[jf][r];
    }
}

// ---- W_eff: plain-sum merge of 4 chunk-partials, then fold w_out ----
__global__ __launch_bounds__(256) void k_weff(const float* __restrict__ ctx4,
                                              const float* __restrict__ sump,
                                              const float* __restrict__ wout,
                                              unsigned short* __restrict__ weff){
  __shared__ float cs[64][65];
  __shared__ float invZ[64];
  int m = blockIdx.x, b = blockIdx.y, z = blockIdx.z;
  int t = threadIdx.x, w = t>>6, l = t&63;
  const size_t chs = (size_t)NB*NHEAD*4096;
  const size_t sts = (size_t)NB*NHEAD*64;
  size_t sb = ((size_t)b*NHEAD + m)*64;
  if (t < 64){
    float Z = sump[sb + t] + sump[sb + sts + t]
            + sump[sb + 2*sts + t] + sump[sb + 3*sts + t];
    invZ[t] = 1.f/Z;
  }
  __syncthreads();
  const float* cb = ctx4 + ((size_t)b*NHEAD + m)*4096;
  for (int idx=t; idx<4096; idx+=256){
    int i = idx>>6;
    cs[i][idx&63] = (cb[idx] + cb[idx+chs] + cb[idx+2*chs] + cb[idx+3*chs]) * invZ[i];
  }
  __syncthreads();
  for (int oo=0;oo<32;++oo){
    int o = z*128 + w*32 + oo;
    float acc = 0.f;
    #pragma unroll
    for (int j=0;j<64;++j) acc += wout[(size_t)o*CDIM + m*64 + j] * cs[l][j];
    weff[((size_t)b*CDIM + o)*CDIM + m*64 + l] = f2bf(acc);
  }
}

// ---- fused final GEMM + bias + channel-LN: 512(o) x 128(n) per block ----
__global__ __launch_bounds__(512) void k_out_ln(const unsigned short* __restrict__ Weff,
                                                const unsigned short* __restrict__ QT,
                                                const float* __restrict__ bias,
                                                const float* __restrict__ g,
                                                float* __restrict__ out){
  __shared__ unsigned short As[512*32];
  __shared__ unsigned short Bs[128*32];
  __shared__ float lnS[128], lnS2[128];
  int b = blockIdx.y, n0 = blockIdx.x*128;
  const unsigned short* Ab = Weff + (size_t)b*CDIM*CDIM;
  const unsigned short* Bb = QT + ((size_t)b*NSEQ + n0)*CDIM;
  int t = threadIdx.x, w = t>>6, l = t&63;
  int lr = l&15, kq = (l>>4)*8;
  f32x4 acc[4][8];
  #pragma unroll
  for (int mi=0;mi<4;mi++)
    #pragma unroll
    for (int ni=0;ni<8;ni++) acc[mi][ni] = (f32x4){0.f,0.f,0.f,0.f};
  for (int k0=0;k0<CDIM;k0+=32){
    #pragma unroll
    for (int it=0;it<4;++it){
      int chunk = it*512 + t;
      int row = chunk>>2, kc = (chunk&3)*8;
      gld_lds16(Ab + (size_t)row*CDIM + k0 + kc, (char*)As + (size_t)chunk*16);
    }
    {
      int row = t>>2, kc = (t&3)*8;
      gld_lds16(Bb + (size_t)row*CDIM + k0 + kc, (char*)Bs + (size_t)t*16);
    }
    __syncthreads();
    short8 af[4], bfv[8];
    #pragma unroll
    for (int mi=0;mi<4;mi++) af[mi]  = *(const short8*)&As[(w*64 + mi*16 + lr)*32 + kq];
    #pragma unroll
    for (int ni=0;ni<8;ni++) bfv[ni] = *(const short8*)&Bs[(ni*16 + lr)*32 + kq];
    #pragma unroll
    for (int mi=0;mi<4;mi++)
      #pragma unroll
      for (int ni=0;ni<8;ni++)
        acc[mi][ni] = __builtin_amdgcn_mfma_f32_16x16x32_bf16(af[mi], bfv[ni], acc[mi][ni], 0, 0, 0);
    __syncthreads();
  }
  if (t < 128){ lnS[t] = 0.f; lnS2[t] = 0.f; }
  __syncthreads();
  float ps[8], ps2[8];
  #pragma unroll
  for (int ni=0;ni<8;ni++){ ps[ni]=0.f; ps2[ni]=0.f; }
  #pragma unroll
  for (int mi=0;mi<4;mi++)
    #pragma unroll
    for (int r=0;r<4;r++){
      int row = w*64 + mi*16 + (l>>4)*4 + r;
      float bb = bias[row];
      #pragma unroll
      for (int ni=0;ni<8;ni++){
        float v = acc[mi][ni][r] + bb;
        acc[mi][ni][r] = v;
        ps[ni] += v; ps2[ni] += v*v;
      }
    }
  #pragma unroll
  for (int ni=0;ni<8;ni++){
    ps[ni]  += __shfl_xor(ps[ni], 16, 64);  ps[ni]  += __shfl_xor(ps[ni], 32, 64);
    ps2[ni] += __shfl_xor(ps2[ni], 16, 64); ps2[ni] += __shfl_xor(ps2[ni], 32, 64);
  }
  if ((l>>4) == 0){
    #pragma unroll
    for (int ni=0;ni<8;ni++){
      atomicAdd(&lnS[ni*16+lr],  ps[ni]);
      atomicAdd(&lnS2[ni*16+lr], ps2[ni]);
    }
  }
  __syncthreads();
  if (t < 128){
    float mean = lnS[t]*(1.f/512.f);
    float var  = lnS2[t]*(1.f/512.f) - mean*mean;
    lnS[t] = mean; lnS2[t] = rsqrtf(var + 1e-5f);
  }
  __syncthreads();
  float* ob = out + (size_t)b*CDIM*NSEQ + n0;
  #pragma unroll
  for (int ni=0;ni<8;ni++){
    int col = ni*16 + lr;
    float mean = lnS[col], rstd = lnS2[col];
    #pragma unroll
    for (int mi=0;mi<4;mi++)
      #pragma unroll
      for (int r=0;r<4;r++){
        int row = w*64 + mi*16 + (l>>4)*4 + r;
        ob[(size_t)row*NSEQ + col] = (acc[mi][ni][r] - mean)*rstd*g[row];
      }
  }
}

extern "C" void kernel_launch(void* const* d_in, const int* in_sizes, int n_in,
                              void* d_out, int out_size, void* d_ws, size_t ws_size,
                              hipStream_t stream){
  const float* x     = (const float*)d_in[0];
  const float* w_qkv = (const float*)d_in[1];
  const float* w_out = (const float*)d_in[2];
  const float* b_out = (const float*)d_in[3];
  const float* g_out = (const float*)d_in[4];
  float* out = (float*)d_out;
  char* ws = (char*)d_ws;

  size_t off = 0;
  unsigned short* wq_bf = (unsigned short*)(ws + off); off += (size_t)O3*CDIM*2;          // 1.5 MB
  char* xT_region = ws + off;                          off += (size_t)NB*NSEQ*CDIM*2;     // 67 MB
  unsigned short* qkv_kv = (unsigned short*)(ws + off); off += (size_t)NB*1024*NSEQ*2;    // 134 MB
  unsigned short* qsmT   = (unsigned short*)(ws + off); off += (size_t)NB*NSEQ*CDIM*2;    // 67 MB
  if (off > ws_size) return;
  unsigned short* xT = (unsigned short*)xT_region;
  // aliases into xT region (xT dead after both GEMMs):
  float* sump = (float*)(xT_region);                        // 128 KB
  float* ctx4 = (float*)(xT_region + (1<<20));              // 8 MB (4 chunks)
  unsigned short* weff = (unsigned short*)(xT_region + (16<<20)); // 8.4 MB

  k_conv_w     <<<O3*CDIM/1024, 256, 0, stream>>>(w_qkv, wq_bf);
  k_transpose_x<<<dim3(NSEQ/64, CDIM/64, NB), 256, 0, stream>>>(x, xT);
  k_gemm_k     <<<dim3(NSEQ/128, 4, NB), 256, 0, stream>>>(wq_bf + (size_t)512*CDIM, xT, qkv_kv);
  k_gemm_v     <<<dim3(NSEQ/128, 4, NB), 256, 0, stream>>>(wq_bf + (size_t)1024*CDIM, xT, qkv_kv);
  k_gemm_q     <<<dim3(NSEQ/128, 4, NB), 256, 0, stream>>>(wq_bf, xT, qsmT);
  k_context    <<<dim3(NHEAD, NB, 4), 256, 0, stream>>>(qkv_kv, ctx4, sump);
  k_weff       <<<dim3(NHEAD, NB, 4), 256, 0, stream>>>(ctx4, sump, w_out, weff);
  k_out_ln     <<<dim3(NSEQ/128, NB), 512, 0, stream>>>(weff, qsmT, b_out, g_out, out);
}